// Round 4
// baseline (289.270 us; speedup 1.0000x reference)
//
#include <hip/hip_runtime.h>
#include <math.h>

#define NN 4096
#define LOG2E 1.4426950408889634f

typedef short short8 __attribute__((ext_vector_type(8)));
typedef float f32x4 __attribute__((ext_vector_type(4)));

// workspace layout (float offsets)
#define OFF_COMB   0u          // 4096*96 = 393216
#define OFF_F1     393216u     // 2*4096 (head-major)
#define OFF_F2     401408u     // 2*4096
#define OFF_MAXF2  409600u     // 2 encoded uints (+pad 16)
#define OFF_W2     409616u     // 32*96
#define OFF_B2     412688u     // 96 (+pad to 412800)
#define OFF_HT     412800u     // bf16 hT[64][4096] = 131072 float slots
#define OFF_PART   543872u     // NS*NN*64, then lpart NS*NN*2

__device__ inline unsigned short f2bf(float x) {
  unsigned u = __float_as_uint(x);
  unsigned r = u + 0x7FFFu + ((u >> 16) & 1u);   // RNE
  return (unsigned short)(r >> 16);
}
__device__ inline unsigned fenc(float f) {
  unsigned b = __float_as_uint(f);
  return (b & 0x80000000u) ? ~b : (b | 0x80000000u);
}
__device__ inline float fdec(unsigned e) {
  return __uint_as_float((e & 0x80000000u) ? (e ^ 0x80000000u) : ~e);
}

// LDS strides chosen for <=4-way bank aliasing with 8B alignment
#define XS 258
#define TS 66
#define GS 12
#define CS 98
#define HS 67

// ---- Kernel 1: embeddings + GAT proj + f1/f2 + hT + maxf2 + (blk64: W2 fold) --
__global__ __launch_bounds__(256) void k_embed2(
    const float* __restrict__ spatial, const float* __restrict__ genomic,
    const float* __restrict__ temporal,
    const float* __restrict__ sp_w, const float* __restrict__ sp_b,
    const float* __restrict__ sp_lg, const float* __restrict__ sp_lb,
    const float* __restrict__ ge_w, const float* __restrict__ ge_b,
    const float* __restrict__ ge_lg, const float* __restrict__ ge_lb,
    const float* __restrict__ te_w, const float* __restrict__ te_b,
    const float* __restrict__ te_lg, const float* __restrict__ te_lb,
    const float* __restrict__ gat_w, const float* __restrict__ gat_a,
    const float* __restrict__ mha_iw, const float* __restrict__ mha_ib,
    const float* __restrict__ mha_ow, const float* __restrict__ mha_ob,
    float* __restrict__ ws)
{
  __shared__ float x_s[64][XS];
  __shared__ float t_s[64][TS];
  __shared__ float g_s[64][GS];
  __shared__ float c_s[64][CS];
  __shared__ float h_s[64][HS];

  int t = threadIdx.x;
  int blk = blockIdx.x;

  if (blk == 64) {
    // ---- W2/B2 fold block: W2[b][col] = sum_r (sum_m iw[b+32m][192+r])*ow[r][col]
    float* fw_s = &x_s[0][0];          // 32*97
    float* ow_s = fw_s + 32 * 97;      // 96*97
    for (int idx = t; idx < 3072; idx += 256) {
      int b = idx / 96, r = idx - b * 96;
      fw_s[b * 97 + r] = mha_iw[b * 288 + 192 + r]
                       + mha_iw[(b + 32) * 288 + 192 + r]
                       + mha_iw[(b + 64) * 288 + 192 + r];
    }
    for (int idx = t; idx < 9216; idx += 256) {
      int r = idx / 96, col = idx - r * 96;
      ow_s[r * 97 + col] = mha_ow[idx];
    }
    if (t < 96) {
      float a = mha_ob[t];
      for (int r = 0; r < 96; r++) a = fmaf(mha_ib[192 + r], mha_ow[r * 96 + t], a);
      ws[OFF_B2 + t] = a;
    }
    __syncthreads();
    int lane = t & 63, wv = t >> 6;
    int b = lane & 31, half = lane >> 5;
    int cb = (wv * 2 + half) * 12;
    float acc[12];
#pragma unroll
    for (int m = 0; m < 12; m++) acc[m] = 0.f;
    for (int r = 0; r < 96; r++) {
      float fv = fw_s[b * 97 + r];
#pragma unroll
      for (int m = 0; m < 12; m++) acc[m] = fmaf(fv, ow_s[r * 97 + cb + m], acc[m]);
    }
#pragma unroll
    for (int m = 0; m < 12; m++) ws[OFF_W2 + b * 96 + cb + m] = acc[m];
    return;
  }

  int row0 = blk * 64;
  int lane = t & 63, wv = t >> 6;

  // ---- stage inputs (coalesced float2) ----
  {
    const float2* xsrc = (const float2*)(spatial + (size_t)row0 * 256);
    for (int idx = t; idx < 64 * 128; idx += 256) {
      float2 v = xsrc[idx];
      int r = idx >> 7, c2 = idx & 127;
      *(float2*)&x_s[r][c2 * 2] = v;
    }
    const float2* tsrc = (const float2*)(temporal + (size_t)row0 * 64);
    for (int idx = t; idx < 64 * 32; idx += 256) {
      float2 v = tsrc[idx];
      int r = idx >> 5, c2 = idx & 31;
      *(float2*)&t_s[r][c2 * 2] = v;
    }
    const float2* gsrc = (const float2*)(genomic + (size_t)row0 * 8);
    for (int idx = t; idx < 64 * 4; idx += 256) {
      float2 v = gsrc[idx];
      int r = idx >> 2, c2 = idx & 3;
      *(float2*)&g_s[r][c2 * 2] = v;
    }
  }
  __syncthreads();

  // ---- three embed GEMMs: lane = row, k uniform -> weights via s_load ----
  int cs = __builtin_amdgcn_readfirstlane(wv * 8);
  {
    float acc[8];
#pragma unroll
    for (int m = 0; m < 8; m++) acc[m] = sp_b[cs + m];
#pragma unroll 4
    for (int k = 0; k < 256; k += 2) {
      float2 xv = *(const float2*)&x_s[lane][k];
#pragma unroll
      for (int m = 0; m < 8; m++) {
        acc[m] = fmaf(xv.x, sp_w[k * 32 + cs + m], acc[m]);
        acc[m] = fmaf(xv.y, sp_w[(k + 1) * 32 + cs + m], acc[m]);
      }
    }
#pragma unroll
    for (int m = 0; m < 8; m++) c_s[lane][cs + m] = acc[m];
  }
  {
    float acc[8];
#pragma unroll
    for (int m = 0; m < 8; m++) acc[m] = ge_b[cs + m];
#pragma unroll
    for (int k = 0; k < 8; k += 2) {
      float2 xv = *(const float2*)&g_s[lane][k];
#pragma unroll
      for (int m = 0; m < 8; m++) {
        acc[m] = fmaf(xv.x, ge_w[k * 32 + cs + m], acc[m]);
        acc[m] = fmaf(xv.y, ge_w[(k + 1) * 32 + cs + m], acc[m]);
      }
    }
#pragma unroll
    for (int m = 0; m < 8; m++) c_s[lane][32 + cs + m] = acc[m];
  }
  {
    float acc[8];
#pragma unroll
    for (int m = 0; m < 8; m++) acc[m] = te_b[cs + m];
#pragma unroll 4
    for (int k = 0; k < 64; k += 2) {
      float2 xv = *(const float2*)&t_s[lane][k];
#pragma unroll
      for (int m = 0; m < 8; m++) {
        acc[m] = fmaf(xv.x, te_w[k * 32 + cs + m], acc[m]);
        acc[m] = fmaf(xv.y, te_w[(k + 1) * 32 + cs + m], acc[m]);
      }
    }
#pragma unroll
    for (int m = 0; m < 8; m++) c_s[lane][64 + cs + m] = acc[m];
  }
  __syncthreads();

  // ---- LN(32-group) + relu, write comb to LDS (in place) + global ----
  {
    int c = t & 31, j = t >> 5;   // 8 job-groups of 32 lanes
    for (int idx = j; idx < 192; idx += 8) {
      int r = idx & 63, grp = idx >> 6;
      float x = c_s[r][grp * 32 + c];
      float s1 = x, s2 = x * x;
      for (int m = 1; m < 32; m <<= 1) {
        s1 += __shfl_xor(s1, m, 32);
        s2 += __shfl_xor(s2, m, 32);
      }
      float mean = s1 * (1.f / 32.f);
      float var  = s2 * (1.f / 32.f) - mean * mean;
      float inv  = rsqrtf(var + 1e-5f);
      const float* lg = (grp == 0) ? sp_lg : (grp == 1) ? ge_lg : te_lg;
      const float* lb = (grp == 0) ? sp_lb : (grp == 1) ? ge_lb : te_lb;
      float y = fmaxf((x - mean) * inv * lg[c] + lb[c], 0.f);
      c_s[r][grp * 32 + c] = y;
      ws[OFF_COMB + (size_t)(row0 + r) * 96 + grp * 32 + c] = y;
    }
  }
  __syncthreads();

  // ---- h = comb @ gat_w (96 -> 64), lane = row, weights via s_load ----
  {
    int cs2 = __builtin_amdgcn_readfirstlane(wv * 16);
    float acc[16];
#pragma unroll
    for (int m = 0; m < 16; m++) acc[m] = 0.f;
#pragma unroll 2
    for (int k = 0; k < 96; k += 2) {
      float2 cv = *(const float2*)&c_s[lane][k];
#pragma unroll
      for (int m = 0; m < 16; m++) {
        acc[m] = fmaf(cv.x, gat_w[k * 64 + cs2 + m], acc[m]);
        acc[m] = fmaf(cv.y, gat_w[(k + 1) * 64 + cs2 + m], acc[m]);
      }
    }
#pragma unroll
    for (int m = 0; m < 16; m++) h_s[lane][cs2 + m] = acc[m];
  }
  __syncthreads();

  // ---- hT (bf16, coalesced) ----
  {
    unsigned short* hT = (unsigned short*)(ws + OFF_HT);
    int j = t & 63, dg = t >> 6;
#pragma unroll
    for (int dd = 0; dd < 16; dd++) {
      int d = dg * 16 + dd;
      hT[(size_t)d * NN + row0 + j] = f2bf(h_s[j][d]);
    }
  }
  // ---- f1/f2 + block-max(f2) via atomic ----
  {
    int r = t & 63, q = t >> 6;
    int head = q & 1, isf2 = q >> 1;
    const float* av = gat_a + (isf2 ? 32 : 0);
    float a = 0.f;
#pragma unroll
    for (int d = 0; d < 32; d++) a = fmaf(h_s[r][head * 32 + d], av[d], a);
    if (!isf2) {
      ws[OFF_F1 + head * NN + row0 + r] = a;
    } else {
      ws[OFF_F2 + head * NN + row0 + r] = a;
      float mx = a;
      for (int m = 1; m < 64; m <<= 1) mx = fmaxf(mx, __shfl_xor(mx, m));
      if (r == 0)
        atomicMax(((unsigned*)(ws + OFF_MAXF2)) + head, fenc(mx));
    }
  }
}

// ---- Kernel 2: GAT via MFMA — scores computed directly in A-fragment layout ---
__global__ __launch_bounds__(256) void k_gat3(
    const int* __restrict__ adj,
    const unsigned short* __restrict__ hT,   // bf16 [d=64][j=4096]
    const float* __restrict__ f1h,           // [head][i]
    const float* __restrict__ f2h,           // [head][j]
    const unsigned* __restrict__ maxf2,      // encoded
    float* __restrict__ part,                // [slot][i][d=64]
    float* __restrict__ lpart, int NS)       // [slot][i][head]
{
  int t = threadIdx.x;
  int lane = t & 63, wv = t >> 6;
  int quad = lane >> 4, mrow = lane & 15;
  int ib = blockIdx.x * 64 + wv * 16;
  int i_lane = ib + mrow;
  int slice = NN / NS;
  int jb = blockIdx.y * slice;

  float f1v0 = f1h[i_lane];
  float f1v1 = f1h[NN + i_lane];
  float s0 = f1v0 + fdec(maxf2[0]), s1 = f1v1 + fdec(maxf2[1]);
  float sh0 = fmaxf(s0, 0.2f * s0);
  float sh1 = fmaxf(s1, 0.2f * s1);
  float c00 = -sh0 * LOG2E;
  float c01 = -sh1 * LOG2E;

  f32x4 acc00 = {0.f, 0.f, 0.f, 0.f};
  f32x4 acc01 = {0.f, 0.f, 0.f, 0.f};
  f32x4 acc10 = {0.f, 0.f, 0.f, 0.f};
  f32x4 acc11 = {0.f, 0.f, 0.f, 0.f};
  float ls0 = 0.f, ls1 = 0.f;

  const int* adjRow = adj + (size_t)i_lane * NN;

#pragma unroll 2
  for (int jc = jb; jc < jb + slice; jc += 32) {
    int jq = jc + quad * 8;
    int4 am0 = *(const int4*)(adjRow + jq);
    int4 am1 = *(const int4*)(adjRow + jq + 4);
    float4 fa = *(const float4*)(f2h + jq);
    float4 fb = *(const float4*)(f2h + jq + 4);
    float4 fc = *(const float4*)(f2h + NN + jq);
    float4 fd = *(const float4*)(f2h + NN + jq + 4);
    short8 b00 = *(const short8*)(hT + (size_t)(mrow)      * NN + jq);
    short8 b01 = *(const short8*)(hT + (size_t)(16 + mrow) * NN + jq);
    short8 b10 = *(const short8*)(hT + (size_t)(32 + mrow) * NN + jq);
    short8 b11 = *(const short8*)(hT + (size_t)(48 + mrow) * NN + jq);

    float f2a[8] = {fa.x, fa.y, fa.z, fa.w, fb.x, fb.y, fb.z, fb.w};
    float f2b[8] = {fc.x, fc.y, fc.z, fc.w, fd.x, fd.y, fd.z, fd.w};
    int   amv[8] = {am0.x, am0.y, am0.z, am0.w, am1.x, am1.y, am1.z, am1.w};

    union { short8 v; unsigned short u[8]; } a0, a1;
#pragma unroll
    for (int k = 0; k < 8; k++) {
      float e0 = f1v0 + f2a[k];
      float le0 = fmaxf(e0, 0.2f * e0);
      float w0 = __builtin_amdgcn_exp2f(fmaf(le0, LOG2E, c00));
      float e1 = f1v1 + f2b[k];
      float le1 = fmaxf(e1, 0.2f * e1);
      float w1 = __builtin_amdgcn_exp2f(fmaf(le1, LOG2E, c01));
      w0 = amv[k] ? w0 : 0.f;
      w1 = amv[k] ? w1 : 0.f;
      ls0 += w0; ls1 += w1;
      a0.u[k] = f2bf(w0);
      a1.u[k] = f2bf(w1);
    }
    acc00 = __builtin_amdgcn_mfma_f32_16x16x32_bf16(a0.v, b00, acc00, 0, 0, 0);
    acc01 = __builtin_amdgcn_mfma_f32_16x16x32_bf16(a0.v, b01, acc01, 0, 0, 0);
    acc10 = __builtin_amdgcn_mfma_f32_16x16x32_bf16(a1.v, b10, acc10, 0, 0, 0);
    acc11 = __builtin_amdgcn_mfma_f32_16x16x32_bf16(a1.v, b11, acc11, 0, 0, 0);
  }

  ls0 += __shfl_xor(ls0, 16); ls0 += __shfl_xor(ls0, 32);
  ls1 += __shfl_xor(ls1, 16); ls1 += __shfl_xor(ls1, 32);

  int slot = blockIdx.y;
#pragma unroll
  for (int r = 0; r < 4; r++) {
    int ig = ib + quad * 4 + r;
    float* p = part + ((size_t)(slot * NN + ig)) * 64;
    p[mrow]      = acc00[r];
    p[16 + mrow] = acc01[r];
    p[32 + mrow] = acc10[r];
    p[48 + mrow] = acc11[r];
  }
  if (lane < 16) {
    int ig = ib + lane;
    lpart[(size_t)(slot * NN + ig) * 2]     = ls0;
    lpart[(size_t)(slot * NN + ig) * 2 + 1] = ls1;
  }
}

// ---------------- Kernel 3: one wave per row — reduce + folded tail + towers ---
__global__ __launch_bounds__(128) void k_post2(
    const float* __restrict__ gat_ow, const float* __restrict__ gat_ob,
    const float* __restrict__ gat_lg, const float* __restrict__ gat_lb,
    const float* __restrict__ m1_w, const float* __restrict__ m1_b,
    const float* __restrict__ m1_lg, const float* __restrict__ m1_lb,
    const float* __restrict__ m2_w, const float* __restrict__ m2_b,
    const float* __restrict__ m2_lg, const float* __restrict__ m2_lb,
    const float* __restrict__ m3_w, const float* __restrict__ m3_b,
    const float* __restrict__ c1_w, const float* __restrict__ c1_b,
    const float* __restrict__ c1_lg, const float* __restrict__ c1_lb,
    const float* __restrict__ c2_w, const float* __restrict__ c2_b,
    const float* __restrict__ c2_lg, const float* __restrict__ c2_lb,
    const float* __restrict__ c3_w, const float* __restrict__ c3_b,
    const float* __restrict__ part, const float* __restrict__ lpart,
    const float* __restrict__ comb, const float* __restrict__ W2,
    const float* __restrict__ B2,
    float* __restrict__ out, int NS)
{
  int t = threadIdx.x;
  int w = t >> 6, l = t & 63;
  int i = blockIdx.x * 2 + w;
  int slots = NS;

  __shared__ float sh_h[2][64];
  __shared__ float sh_go[2][32];
  __shared__ float sh_fin[2][96];
  __shared__ float sh_t1[2][2][64];

  float a = 0.f;
  for (int s = 0; s < slots; s++) a += part[((size_t)(s * NN + i)) * 64 + l];
  float l0 = 0.f, l1 = 0.f;
  for (int s = 0; s < slots; s++) {
    l0 += lpart[(size_t)(s * NN + i) * 2];
    l1 += lpart[(size_t)(s * NN + i) * 2 + 1];
  }
  sh_h[w][l] = a / (l < 32 ? l0 : l1);
  __syncthreads();

  if (l < 32) {
    float acc = gat_ob[l];
    for (int r = 0; r < 64; r++) acc = fmaf(sh_h[w][r], gat_ow[r * 32 + l], acc);
    float s1 = acc, s2 = acc * acc;
    for (int m = 1; m < 32; m <<= 1) {
      s1 += __shfl_xor(s1, m, 32);
      s2 += __shfl_xor(s2, m, 32);
    }
    float mean = s1 * (1.f / 32.f), var = s2 * (1.f / 32.f) - mean * mean;
    sh_go[w][l] = (acc - mean) * rsqrtf(var + 1e-5f) * gat_lg[l] + gat_lb[l];
  }
  __syncthreads();

  {
    float accA = B2[l];
    for (int d = 0; d < 32; d++) accA = fmaf(sh_go[w][d], W2[d * 96 + l], accA);
    sh_fin[w][l] = accA + comb[(size_t)i * 96 + l];
    if (l < 32) {
      float accB = B2[64 + l];
      for (int d = 0; d < 32; d++) accB = fmaf(sh_go[w][d], W2[d * 96 + 64 + l], accB);
      sh_fin[w][64 + l] = accB + comb[(size_t)i * 96 + 64 + l];
    }
  }
  __syncthreads();

  {
    float am = m1_b[l], ac = c1_b[l];
    for (int r = 0; r < 96; r++) {
      float f = sh_fin[w][r];
      am = fmaf(f, m1_w[r * 64 + l], am);
      ac = fmaf(f, c1_w[r * 64 + l], ac);
    }
    float s1 = am, s2 = am * am;
    for (int m = 1; m < 64; m <<= 1) { s1 += __shfl_xor(s1, m); s2 += __shfl_xor(s2, m); }
    float mean = s1 * (1.f / 64.f), var = s2 * (1.f / 64.f) - mean * mean;
    sh_t1[w][0][l] = fmaxf((am - mean) * rsqrtf(var + 1e-5f) * m1_lg[l] + m1_lb[l], 0.f);
    s1 = ac; s2 = ac * ac;
    for (int m = 1; m < 64; m <<= 1) { s1 += __shfl_xor(s1, m); s2 += __shfl_xor(s2, m); }
    mean = s1 * (1.f / 64.f); var = s2 * (1.f / 64.f) - mean * mean;
    sh_t1[w][1][l] = fmaxf((ac - mean) * rsqrtf(var + 1e-5f) * c1_lg[l] + c1_lb[l], 0.f);
  }
  __syncthreads();

  {
    int tw = l >> 5, c = l & 31;
    const float* w2  = tw ? c2_w  : m2_w;
    const float* b2  = tw ? c2_b  : m2_b;
    const float* lg2 = tw ? c2_lg : m2_lg;
    const float* lb2 = tw ? c2_lb : m2_lb;
    float a2 = b2[c];
    for (int r = 0; r < 64; r++) a2 = fmaf(sh_t1[w][tw][r], w2[r * 32 + c], a2);
    float u1 = a2, u2 = a2 * a2;
    for (int m = 1; m < 32; m <<= 1) {
      u1 += __shfl_xor(u1, m, 32);
      u2 += __shfl_xor(u2, m, 32);
    }
    float mean = u1 * (1.f / 32.f), var = u2 * (1.f / 32.f) - mean * mean;
    float y2 = fmaxf((a2 - mean) * rsqrtf(var + 1e-5f) * lg2[c] + lb2[c], 0.f);
    float p = y2 * (tw ? c3_w[c] : m3_w[c]);
    for (int m = 1; m < 32; m <<= 1) p += __shfl_xor(p, m, 32);
    if (c == 0) {
      float v = p + (tw ? c3_b[0] : m3_b[0]);
      if (tw) out[NN + i] = 1.f / (1.f + expf(-v));
      else    out[i] = v;
    }
  }
}

extern "C" void kernel_launch(void* const* d_in, const int* in_sizes, int n_in,
                              void* d_out, int out_size, void* d_ws, size_t ws_size,
                              hipStream_t stream) {
  (void)in_sizes; (void)n_in; (void)out_size;
  const float* spatial  = (const float*)d_in[0];
  const float* genomic  = (const float*)d_in[1];
  const float* temporal = (const float*)d_in[2];
  const int*   adj      = (const int*)d_in[3];
  const float* sp_w = (const float*)d_in[4];
  const float* sp_b = (const float*)d_in[5];
  const float* sp_lg = (const float*)d_in[6];
  const float* sp_lb = (const float*)d_in[7];
  const float* ge_w = (const float*)d_in[8];
  const float* ge_b = (const float*)d_in[9];
  const float* ge_lg = (const float*)d_in[10];
  const float* ge_lb = (const float*)d_in[11];
  const float* te_w = (const float*)d_in[12];
  const float* te_b = (const float*)d_in[13];
  const float* te_lg = (const float*)d_in[14];
  const float* te_lb = (const float*)d_in[15];
  const float* gat_w = (const float*)d_in[16];
  const float* gat_a = (const float*)d_in[17];
  const float* gat_ow = (const float*)d_in[18];
  const float* gat_ob = (const float*)d_in[19];
  const float* gat_lg = (const float*)d_in[20];
  const float* gat_lb = (const float*)d_in[21];
  const float* mha_iw = (const float*)d_in[22];
  const float* mha_ib = (const float*)d_in[23];
  const float* mha_ow = (const float*)d_in[24];
  const float* mha_ob = (const float*)d_in[25];
  const float* m1_w = (const float*)d_in[26];
  const float* m1_b = (const float*)d_in[27];
  const float* m1_lg = (const float*)d_in[28];
  const float* m1_lb = (const float*)d_in[29];
  const float* m2_w = (const float*)d_in[30];
  const float* m2_b = (const float*)d_in[31];
  const float* m2_lg = (const float*)d_in[32];
  const float* m2_lb = (const float*)d_in[33];
  const float* m3_w = (const float*)d_in[34];
  const float* m3_b = (const float*)d_in[35];
  const float* c1_w = (const float*)d_in[36];
  const float* c1_b = (const float*)d_in[37];
  const float* c1_lg = (const float*)d_in[38];
  const float* c1_lb = (const float*)d_in[39];
  const float* c2_w = (const float*)d_in[40];
  const float* c2_b = (const float*)d_in[41];
  const float* c2_lg = (const float*)d_in[42];
  const float* c2_lb = (const float*)d_in[43];
  const float* c3_w = (const float*)d_in[44];
  const float* c3_b = (const float*)d_in[45];

  float* ws  = (float*)d_ws;
  float* out = (float*)d_out;

  int NS = 16;
  while (NS > 1) {
    size_t need = (size_t)(OFF_PART + (size_t)NS * NN * 64 + (size_t)NS * NN * 2) * 4;
    if (need <= ws_size) break;
    NS >>= 1;
  }
  float* part  = ws + OFF_PART;
  float* lpart = part + (size_t)NS * NN * 64;

  // init maxf2 atomic slots (encoded-uint 0 == -inf sentinel)
  hipMemsetAsync((char*)d_ws + (size_t)OFF_MAXF2 * 4, 0, 16, stream);

  k_embed2<<<65, 256, 0, stream>>>(spatial, genomic, temporal,
                                   sp_w, sp_b, sp_lg, sp_lb,
                                   ge_w, ge_b, ge_lg, ge_lb,
                                   te_w, te_b, te_lg, te_lb,
                                   gat_w, gat_a,
                                   mha_iw, mha_ib, mha_ow, mha_ob, ws);
  dim3 g2(NN / 64, NS);
  k_gat3<<<g2, 256, 0, stream>>>(adj,
                                 (const unsigned short*)(ws + OFF_HT),
                                 ws + OFF_F1, ws + OFF_F2,
                                 (const unsigned*)(ws + OFF_MAXF2),
                                 part, lpart, NS);
  k_post2<<<NN / 2, 128, 0, stream>>>(gat_ow, gat_ob, gat_lg, gat_lb,
                                      m1_w, m1_b, m1_lg, m1_lb,
                                      m2_w, m2_b, m2_lg, m2_lb,
                                      m3_w, m3_b,
                                      c1_w, c1_b, c1_lg, c1_lb,
                                      c2_w, c2_b, c2_lg, c2_lb,
                                      c3_w, c3_b,
                                      part, lpart, ws + OFF_COMB,
                                      ws + OFF_W2, ws + OFF_B2,
                                      out, NS);
}

// Round 5
// 260.288 us; speedup vs baseline: 1.1113x; 1.1113x over previous
//
#include <hip/hip_runtime.h>
#include <math.h>

#define NN 4096
#define LOG2E 1.4426950408889634f

typedef short short8 __attribute__((ext_vector_type(8)));
typedef float f32x4 __attribute__((ext_vector_type(4)));

// workspace layout (float offsets)
#define OFF_COMB   0u          // 4096*96
#define OFF_F1     393216u     // [head][i] 2*4096
#define OFF_F2     401408u     // [head][j] 2*4096
#define OFF_MAXF2  409600u     // 2 floats (+pad)
#define OFF_W2     409616u     // 32*96
#define OFF_B2     412688u     // 96 (+pad to 412800)
#define OFF_HT     412800u     // bf16 hT[64][4096] = 131072 float slots
#define OFF_PART   543872u     // part[i][NS][64], then lpart[i][NS][2]

__device__ inline unsigned short f2bf(float x) {
  unsigned u = __float_as_uint(x);
  unsigned r = u + 0x7FFFu + ((u >> 16) & 1u);   // RNE
  return (unsigned short)(r >> 16);
}

// ---- Kernel 1: comb = relu(LN(embed)) for all 3 groups; tail blocks fold W2/B2.
// One output element per thread; half-wave (32 lanes) = one (row, group) job.
__global__ __launch_bounds__(256) void k_comb(
    const float* __restrict__ spatial, const float* __restrict__ genomic,
    const float* __restrict__ temporal,
    const float* __restrict__ sp_w, const float* __restrict__ sp_b,
    const float* __restrict__ sp_lg, const float* __restrict__ sp_lb,
    const float* __restrict__ ge_w, const float* __restrict__ ge_b,
    const float* __restrict__ ge_lg, const float* __restrict__ ge_lb,
    const float* __restrict__ te_w, const float* __restrict__ te_b,
    const float* __restrict__ te_lg, const float* __restrict__ te_lb,
    const float* __restrict__ mha_iw, const float* __restrict__ mha_ib,
    const float* __restrict__ mha_ow, const float* __restrict__ mha_ob,
    float* __restrict__ ws)
{
  int t = threadIdx.x;
  int blk = blockIdx.x;

  if (blk >= 1536) {
    if (blk < 1548) {
      // W2[b][col] = sum_r (iw[b][192+r]+iw[b+32][192+r]+iw[b+64][192+r]) * ow[r][col]
      int idx = (blk - 1536) * 256 + t;   // [0, 3072)
      int b = idx / 96, col = idx - b * 96;
      float acc = 0.f;
      for (int r = 0; r < 96; r++) {
        float fw = mha_iw[b * 288 + 192 + r]
                 + mha_iw[(b + 32) * 288 + 192 + r]
                 + mha_iw[(b + 64) * 288 + 192 + r];
        acc = fmaf(fw, mha_ow[r * 96 + col], acc);
      }
      ws[OFF_W2 + b * 96 + col] = acc;
    } else {
      if (t < 96) {
        float acc = mha_ob[t];
        for (int r = 0; r < 96; r++) acc = fmaf(mha_ib[192 + r], mha_ow[r * 96 + t], acc);
        ws[OFF_B2 + t] = acc;
      }
    }
    return;
  }

  int j = blk * 8 + (t >> 5);      // job id [0, 12288)
  int grp = j >> 12;               // 0 spatial, 1 genomic, 2 temporal
  int row = j & 4095;
  int c = t & 31;

  float val;
  const float* lg;
  const float* lb;
  if (grp == 0) {
    const float* in = spatial + (size_t)row * 256;
    float a0 = 0.f, a1 = 0.f, a2 = 0.f, a3 = 0.f;
#pragma unroll 4
    for (int k = 0; k < 256; k += 4) {
      float4 x = *(const float4*)(in + k);
      a0 = fmaf(x.x, sp_w[(k)     * 32 + c], a0);
      a1 = fmaf(x.y, sp_w[(k + 1) * 32 + c], a1);
      a2 = fmaf(x.z, sp_w[(k + 2) * 32 + c], a2);
      a3 = fmaf(x.w, sp_w[(k + 3) * 32 + c], a3);
    }
    val = sp_b[c] + ((a0 + a1) + (a2 + a3));
    lg = sp_lg; lb = sp_lb;
  } else if (grp == 1) {
    const float* in = genomic + (size_t)row * 8;
    float4 x0 = *(const float4*)(in);
    float4 x1 = *(const float4*)(in + 4);
    float a0 = ge_b[c];
    a0 = fmaf(x0.x, ge_w[0 * 32 + c], a0);
    a0 = fmaf(x0.y, ge_w[1 * 32 + c], a0);
    a0 = fmaf(x0.z, ge_w[2 * 32 + c], a0);
    a0 = fmaf(x0.w, ge_w[3 * 32 + c], a0);
    a0 = fmaf(x1.x, ge_w[4 * 32 + c], a0);
    a0 = fmaf(x1.y, ge_w[5 * 32 + c], a0);
    a0 = fmaf(x1.z, ge_w[6 * 32 + c], a0);
    a0 = fmaf(x1.w, ge_w[7 * 32 + c], a0);
    val = a0;
    lg = ge_lg; lb = ge_lb;
  } else {
    const float* in = temporal + (size_t)row * 64;
    float a0 = 0.f, a1 = 0.f, a2 = 0.f, a3 = 0.f;
#pragma unroll 4
    for (int k = 0; k < 64; k += 4) {
      float4 x = *(const float4*)(in + k);
      a0 = fmaf(x.x, te_w[(k)     * 32 + c], a0);
      a1 = fmaf(x.y, te_w[(k + 1) * 32 + c], a1);
      a2 = fmaf(x.z, te_w[(k + 2) * 32 + c], a2);
      a3 = fmaf(x.w, te_w[(k + 3) * 32 + c], a3);
    }
    val = te_b[c] + ((a0 + a1) + (a2 + a3));
    lg = te_lg; lb = te_lb;
  }

  // LayerNorm over the 32 cols of this group (exactly this half-wave)
  float s1 = val, s2 = val * val;
#pragma unroll
  for (int m = 1; m < 32; m <<= 1) {
    s1 += __shfl_xor(s1, m, 32);
    s2 += __shfl_xor(s2, m, 32);
  }
  float mean = s1 * (1.f / 32.f);
  float var  = s2 * (1.f / 32.f) - mean * mean;
  float y = fmaxf((val - mean) * rsqrtf(var + 1e-5f) * lg[c] + lb[c], 0.f);
  ws[OFF_COMB + (size_t)row * 96 + grp * 32 + c] = y;
}

// ---- Kernel 2: h = comb @ gat_w; hT bf16 transpose; f1/f2 -----------------
__global__ __launch_bounds__(256) void k_proj(
    const float* __restrict__ gat_w, const float* __restrict__ gat_a,
    float* __restrict__ ws)
{
  __shared__ float h_s[4][64];
  int t = threadIdx.x;
  int w = t >> 6, d = t & 63;
  int row0 = blockIdx.x * 4;
  int row = row0 + w;

  const float* crow = ws + OFF_COMB + (size_t)row * 96;
  float a0 = 0.f, a1 = 0.f;
#pragma unroll 8
  for (int k = 0; k < 96; k += 2) {
    a0 = fmaf(crow[k],     gat_w[k * 64 + d],       a0);
    a1 = fmaf(crow[k + 1], gat_w[(k + 1) * 64 + d], a1);
  }
  float h = a0 + a1;

  // f1/f2 per head via half-wave reduction
  int dc = d & 31;
  float p1 = h * gat_a[dc];
  float p2 = h * gat_a[32 + dc];
#pragma unroll
  for (int m = 1; m < 32; m <<= 1) {
    p1 += __shfl_xor(p1, m, 32);
    p2 += __shfl_xor(p2, m, 32);
  }
  if (dc == 0) {
    int head = d >> 5;
    ws[OFF_F1 + head * NN + row] = p1;
    ws[OFF_F2 + head * NN + row] = p2;
  }

  h_s[w][d] = h;
  __syncthreads();
  if (t < 64) {
    unsigned u0 = (unsigned)f2bf(h_s[0][t]) | ((unsigned)f2bf(h_s[1][t]) << 16);
    unsigned u1 = (unsigned)f2bf(h_s[2][t]) | ((unsigned)f2bf(h_s[3][t]) << 16);
    uint2 v; v.x = u0; v.y = u1;
    unsigned short* hT = (unsigned short*)(ws + OFF_HT);
    *(uint2*)(hT + (size_t)t * NN + row0) = v;
  }
}

// ---- Kernel 2b: global max of f2 per head (one block) ---------------------
__global__ __launch_bounds__(256) void k_max(float* __restrict__ ws)
{
  __shared__ float red[4][2];
  int t = threadIdx.x;
  const float4* p0 = (const float4*)(ws + OFF_F2);
  const float4* p1 = (const float4*)(ws + OFF_F2 + NN);
  float m0 = -1e30f, m1 = -1e30f;
#pragma unroll
  for (int q = 0; q < 4; q++) {
    float4 v0 = p0[t + q * 256];
    float4 v1 = p1[t + q * 256];
    m0 = fmaxf(m0, fmaxf(fmaxf(v0.x, v0.y), fmaxf(v0.z, v0.w)));
    m1 = fmaxf(m1, fmaxf(fmaxf(v1.x, v1.y), fmaxf(v1.z, v1.w)));
  }
#pragma unroll
  for (int m = 1; m < 64; m <<= 1) {
    m0 = fmaxf(m0, __shfl_xor(m0, m));
    m1 = fmaxf(m1, __shfl_xor(m1, m));
  }
  if ((t & 63) == 0) { red[t >> 6][0] = m0; red[t >> 6][1] = m1; }
  __syncthreads();
  if (t == 0) {
    float r0 = red[0][0], r1 = red[0][1];
    for (int q = 1; q < 4; q++) { r0 = fmaxf(r0, red[q][0]); r1 = fmaxf(r1, red[q][1]); }
    ws[OFF_MAXF2] = r0;
    ws[OFF_MAXF2 + 1] = r1;
  }
}

// ---- Kernel 3: GAT via MFMA — scores computed directly in A-fragment layout --
__global__ __launch_bounds__(256) void k_gat3(
    const int* __restrict__ adj,
    const unsigned short* __restrict__ hT,   // bf16 [d=64][j=4096]
    const float* __restrict__ f1h,           // [head][i]
    const float* __restrict__ f2h,           // [head][j]
    const float* __restrict__ maxf2,
    float* __restrict__ part,                // [i][slot][64]
    float* __restrict__ lpart, int NS)       // [i][slot][2]
{
  int t = threadIdx.x;
  int lane = t & 63, wv = t >> 6;
  int quad = lane >> 4, mrow = lane & 15;
  int ib = blockIdx.x * 64 + wv * 16;
  int i_lane = ib + mrow;
  int slice = NN / NS;
  int jb = blockIdx.y * slice;

  float f1v0 = f1h[i_lane];
  float f1v1 = f1h[NN + i_lane];
  float s0 = f1v0 + maxf2[0], s1 = f1v1 + maxf2[1];
  float sh0 = fmaxf(s0, 0.2f * s0);   // >= max_j leaky(f1+f2), leaky monotonic
  float sh1 = fmaxf(s1, 0.2f * s1);
  float c00 = -sh0 * LOG2E;
  float c01 = -sh1 * LOG2E;

  f32x4 acc00 = {0.f, 0.f, 0.f, 0.f};
  f32x4 acc01 = {0.f, 0.f, 0.f, 0.f};
  f32x4 acc10 = {0.f, 0.f, 0.f, 0.f};
  f32x4 acc11 = {0.f, 0.f, 0.f, 0.f};
  float ls0 = 0.f, ls1 = 0.f;

  const int* adjRow = adj + (size_t)i_lane * NN;

#pragma unroll 2
  for (int jc = jb; jc < jb + slice; jc += 32) {
    int jq = jc + quad * 8;
    int4 am0 = *(const int4*)(adjRow + jq);
    int4 am1 = *(const int4*)(adjRow + jq + 4);
    float4 fa = *(const float4*)(f2h + jq);
    float4 fb = *(const float4*)(f2h + jq + 4);
    float4 fc = *(const float4*)(f2h + NN + jq);
    float4 fd = *(const float4*)(f2h + NN + jq + 4);
    short8 b00 = *(const short8*)(hT + (size_t)(mrow)      * NN + jq);
    short8 b01 = *(const short8*)(hT + (size_t)(16 + mrow) * NN + jq);
    short8 b10 = *(const short8*)(hT + (size_t)(32 + mrow) * NN + jq);
    short8 b11 = *(const short8*)(hT + (size_t)(48 + mrow) * NN + jq);

    float f2a[8] = {fa.x, fa.y, fa.z, fa.w, fb.x, fb.y, fb.z, fb.w};
    float f2b[8] = {fc.x, fc.y, fc.z, fc.w, fd.x, fd.y, fd.z, fd.w};
    int   amv[8] = {am0.x, am0.y, am0.z, am0.w, am1.x, am1.y, am1.z, am1.w};

    union { short8 v; unsigned short u[8]; } a0, a1;
#pragma unroll
    for (int k = 0; k < 8; k++) {
      float e0 = f1v0 + f2a[k];
      float le0 = fmaxf(e0, 0.2f * e0);
      float w0 = __builtin_amdgcn_exp2f(fmaf(le0, LOG2E, c00));
      float e1 = f1v1 + f2b[k];
      float le1 = fmaxf(e1, 0.2f * e1);
      float w1 = __builtin_amdgcn_exp2f(fmaf(le1, LOG2E, c01));
      w0 = amv[k] ? w0 : 0.f;
      w1 = amv[k] ? w1 : 0.f;
      ls0 += w0; ls1 += w1;
      a0.u[k] = f2bf(w0);
      a1.u[k] = f2bf(w1);
    }
    acc00 = __builtin_amdgcn_mfma_f32_16x16x32_bf16(a0.v, b00, acc00, 0, 0, 0);
    acc01 = __builtin_amdgcn_mfma_f32_16x16x32_bf16(a0.v, b01, acc01, 0, 0, 0);
    acc10 = __builtin_amdgcn_mfma_f32_16x16x32_bf16(a1.v, b10, acc10, 0, 0, 0);
    acc11 = __builtin_amdgcn_mfma_f32_16x16x32_bf16(a1.v, b11, acc11, 0, 0, 0);
  }

  ls0 += __shfl_xor(ls0, 16); ls0 += __shfl_xor(ls0, 32);
  ls1 += __shfl_xor(ls1, 16); ls1 += __shfl_xor(ls1, 32);

  int slot = blockIdx.y;
#pragma unroll
  for (int r = 0; r < 4; r++) {
    int ig = ib + quad * 4 + r;
    float* p = part + (size_t)ig * (NS * 64) + slot * 64;
    p[mrow]      = acc00[r];
    p[16 + mrow] = acc01[r];
    p[32 + mrow] = acc10[r];
    p[48 + mrow] = acc11[r];
  }
  if (lane < 16) {
    int ig = ib + lane;
    lpart[((size_t)ig * NS + slot) * 2]     = ls0;
    lpart[((size_t)ig * NS + slot) * 2 + 1] = ls1;
  }
}

// ---- Kernel 4: one wave per row — reduce + folded tail + towers ------------
__global__ __launch_bounds__(256) void k_post2(
    const float* __restrict__ gat_ow, const float* __restrict__ gat_ob,
    const float* __restrict__ gat_lg, const float* __restrict__ gat_lb,
    const float* __restrict__ m1_w, const float* __restrict__ m1_b,
    const float* __restrict__ m1_lg, const float* __restrict__ m1_lb,
    const float* __restrict__ m2_w, const float* __restrict__ m2_b,
    const float* __restrict__ m2_lg, const float* __restrict__ m2_lb,
    const float* __restrict__ m3_w, const float* __restrict__ m3_b,
    const float* __restrict__ c1_w, const float* __restrict__ c1_b,
    const float* __restrict__ c1_lg, const float* __restrict__ c1_lb,
    const float* __restrict__ c2_w, const float* __restrict__ c2_b,
    const float* __restrict__ c2_lg, const float* __restrict__ c2_lb,
    const float* __restrict__ c3_w, const float* __restrict__ c3_b,
    const float* __restrict__ part, const float* __restrict__ lpart,
    const float* __restrict__ comb, const float* __restrict__ W2,
    const float* __restrict__ B2,
    float* __restrict__ out, int NS)
{
  int t = threadIdx.x;
  int w = t >> 6, l = t & 63;
  int i = blockIdx.x * 4 + w;

  __shared__ float sh_h[4][64];
  __shared__ float sh_go[4][32];
  __shared__ float sh_fin[4][96];
  __shared__ float sh_t1[4][2][64];

  // phase 1: reduce partials (contiguous 4KB per row)
  {
    const float* pr = part + (size_t)i * (NS * 64);
    float a0 = 0.f, a1 = 0.f, a2 = 0.f, a3 = 0.f;
#pragma unroll
    for (int s = 0; s < 16; s += 4) {
      a0 += pr[(s)     * 64 + l];
      a1 += pr[(s + 1) * 64 + l];
      a2 += pr[(s + 2) * 64 + l];
      a3 += pr[(s + 3) * 64 + l];
    }
    float a = (a0 + a1) + (a2 + a3);
    const float* lr = lpart + (size_t)i * NS * 2;
    float l0 = 0.f, l1 = 0.f;
#pragma unroll
    for (int s = 0; s < 16; s++) { l0 += lr[s * 2]; l1 += lr[s * 2 + 1]; }
    sh_h[w][l] = a / (l < 32 ? l0 : l1);
  }
  __syncthreads();

  // phase 2: gat_out = LN32(h_out @ gat_ow + ob)
  if (l < 32) {
    float acc = gat_ob[l];
#pragma unroll 8
    for (int r = 0; r < 64; r++) acc = fmaf(sh_h[w][r], gat_ow[r * 32 + l], acc);
    float s1 = acc, s2 = acc * acc;
#pragma unroll
    for (int m = 1; m < 32; m <<= 1) {
      s1 += __shfl_xor(s1, m, 32);
      s2 += __shfl_xor(s2, m, 32);
    }
    float mean = s1 * (1.f / 32.f), var = s2 * (1.f / 32.f) - mean * mean;
    sh_go[w][l] = (acc - mean) * rsqrtf(var + 1e-5f) * gat_lg[l] + gat_lb[l];
  }
  __syncthreads();

  // phase 3: final = gat_out @ W2 + B2 + combined
  {
    float accA = B2[l];
#pragma unroll 8
    for (int d = 0; d < 32; d++) accA = fmaf(sh_go[w][d], W2[d * 96 + l], accA);
    sh_fin[w][l] = accA + comb[(size_t)i * 96 + l];
    if (l < 32) {
      float accB = B2[64 + l];
#pragma unroll 8
      for (int d = 0; d < 32; d++) accB = fmaf(sh_go[w][d], W2[d * 96 + 64 + l], accB);
      sh_fin[w][64 + l] = accB + comb[(size_t)i * 96 + 64 + l];
    }
  }
  __syncthreads();

  // phase 4: tower layer 1 for both towers
  {
    float am = m1_b[l], ac = c1_b[l];
#pragma unroll 4
    for (int r = 0; r < 96; r++) {
      float f = sh_fin[w][r];
      am = fmaf(f, m1_w[r * 64 + l], am);
      ac = fmaf(f, c1_w[r * 64 + l], ac);
    }
    float s1 = am, s2 = am * am;
#pragma unroll
    for (int m = 1; m < 64; m <<= 1) { s1 += __shfl_xor(s1, m); s2 += __shfl_xor(s2, m); }
    float mean = s1 * (1.f / 64.f), var = s2 * (1.f / 64.f) - mean * mean;
    sh_t1[w][0][l] = fmaxf((am - mean) * rsqrtf(var + 1e-5f) * m1_lg[l] + m1_lb[l], 0.f);
    s1 = ac; s2 = ac * ac;
#pragma unroll
    for (int m = 1; m < 64; m <<= 1) { s1 += __shfl_xor(s1, m); s2 += __shfl_xor(s2, m); }
    mean = s1 * (1.f / 64.f); var = s2 * (1.f / 64.f) - mean * mean;
    sh_t1[w][1][l] = fmaxf((ac - mean) * rsqrtf(var + 1e-5f) * c1_lg[l] + c1_lb[l], 0.f);
  }
  __syncthreads();

  // phase 5: tower layer 2 (lanes 0-31 motor, 32-63 cognitive) + output
  {
    int tw = l >> 5, c = l & 31;
    const float* w2  = tw ? c2_w  : m2_w;
    const float* b2  = tw ? c2_b  : m2_b;
    const float* lg2 = tw ? c2_lg : m2_lg;
    const float* lb2 = tw ? c2_lb : m2_lb;
    float a2 = b2[c];
#pragma unroll 4
    for (int r = 0; r < 64; r++) a2 = fmaf(sh_t1[w][tw][r], w2[r * 32 + c], a2);
    float u1 = a2, u2 = a2 * a2;
#pragma unroll
    for (int m = 1; m < 32; m <<= 1) {
      u1 += __shfl_xor(u1, m, 32);
      u2 += __shfl_xor(u2, m, 32);
    }
    float mean = u1 * (1.f / 32.f), var = u2 * (1.f / 32.f) - mean * mean;
    float y2 = fmaxf((a2 - mean) * rsqrtf(var + 1e-5f) * lg2[c] + lb2[c], 0.f);
    float p = y2 * (tw ? c3_w[c] : m3_w[c]);
#pragma unroll
    for (int m = 1; m < 32; m <<= 1) p += __shfl_xor(p, m, 32);
    if (c == 0) {
      float v = p + (tw ? c3_b[0] : m3_b[0]);
      if (tw) out[NN + i] = 1.f / (1.f + expf(-v));
      else    out[i] = v;
    }
  }
}

extern "C" void kernel_launch(void* const* d_in, const int* in_sizes, int n_in,
                              void* d_out, int out_size, void* d_ws, size_t ws_size,
                              hipStream_t stream) {
  (void)in_sizes; (void)n_in; (void)out_size;
  const float* spatial  = (const float*)d_in[0];
  const float* genomic  = (const float*)d_in[1];
  const float* temporal = (const float*)d_in[2];
  const int*   adj      = (const int*)d_in[3];
  const float* sp_w = (const float*)d_in[4];
  const float* sp_b = (const float*)d_in[5];
  const float* sp_lg = (const float*)d_in[6];
  const float* sp_lb = (const float*)d_in[7];
  const float* ge_w = (const float*)d_in[8];
  const float* ge_b = (const float*)d_in[9];
  const float* ge_lg = (const float*)d_in[10];
  const float* ge_lb = (const float*)d_in[11];
  const float* te_w = (const float*)d_in[12];
  const float* te_b = (const float*)d_in[13];
  const float* te_lg = (const float*)d_in[14];
  const float* te_lb = (const float*)d_in[15];
  const float* gat_w = (const float*)d_in[16];
  const float* gat_a = (const float*)d_in[17];
  const float* gat_ow = (const float*)d_in[18];
  const float* gat_ob = (const float*)d_in[19];
  const float* gat_lg = (const float*)d_in[20];
  const float* gat_lb = (const float*)d_in[21];
  const float* mha_iw = (const float*)d_in[22];
  const float* mha_ib = (const float*)d_in[23];
  const float* mha_ow = (const float*)d_in[24];
  const float* mha_ob = (const float*)d_in[25];
  const float* m1_w = (const float*)d_in[26];
  const float* m1_b = (const float*)d_in[27];
  const float* m1_lg = (const float*)d_in[28];
  const float* m1_lb = (const float*)d_in[29];
  const float* m2_w = (const float*)d_in[30];
  const float* m2_b = (const float*)d_in[31];
  const float* m2_lg = (const float*)d_in[32];
  const float* m2_lb = (const float*)d_in[33];
  const float* m3_w = (const float*)d_in[34];
  const float* m3_b = (const float*)d_in[35];
  const float* c1_w = (const float*)d_in[36];
  const float* c1_b = (const float*)d_in[37];
  const float* c1_lg = (const float*)d_in[38];
  const float* c1_lb = (const float*)d_in[39];
  const float* c2_w = (const float*)d_in[40];
  const float* c2_b = (const float*)d_in[41];
  const float* c2_lg = (const float*)d_in[42];
  const float* c2_lb = (const float*)d_in[43];
  const float* c3_w = (const float*)d_in[44];
  const float* c3_b = (const float*)d_in[45];

  float* ws  = (float*)d_ws;
  float* out = (float*)d_out;

  int NS = 16;
  while (NS > 1) {
    size_t need = (size_t)(OFF_PART + (size_t)NS * NN * 64 + (size_t)NS * NN * 2) * 4;
    if (need <= ws_size) break;
    NS >>= 1;
  }
  float* part  = ws + OFF_PART;
  float* lpart = part + (size_t)NS * NN * 64;

  k_comb<<<1549, 256, 0, stream>>>(spatial, genomic, temporal,
                                   sp_w, sp_b, sp_lg, sp_lb,
                                   ge_w, ge_b, ge_lg, ge_lb,
                                   te_w, te_b, te_lg, te_lb,
                                   mha_iw, mha_ib, mha_ow, mha_ob, ws);
  k_proj<<<NN / 4, 256, 0, stream>>>(gat_w, gat_a, ws);
  k_max<<<1, 256, 0, stream>>>(ws);
  dim3 g2(NN / 64, NS);
  k_gat3<<<g2, 256, 0, stream>>>(adj,
                                 (const unsigned short*)(ws + OFF_HT),
                                 ws + OFF_F1, ws + OFF_F2, ws + OFF_MAXF2,
                                 part, lpart, NS);
  k_post2<<<NN / 4, 256, 0, stream>>>(gat_ow, gat_ob, gat_lg, gat_lb,
                                      m1_w, m1_b, m1_lg, m1_lb,
                                      m2_w, m2_b, m2_lg, m2_lb,
                                      m3_w, m3_b,
                                      c1_w, c1_b, c1_lg, c1_lb,
                                      c2_w, c2_b, c2_lg, c2_lb,
                                      c3_w, c3_b,
                                      part, lpart, ws + OFF_COMB,
                                      ws + OFF_W2, ws + OFF_B2,
                                      out, NS);
}